// Round 1
// baseline (37.601 us; speedup 1.0000x reference)
//
#include <hip/hip_runtime.h>

#define B_ROWS   256
#define SPLIT    8          // blocks per row
#define NTHREADS 256        // 4 waves

// ---------------------------------------------------------------------------
// Kernel 1: per-(row,segment) partial sums of {x, y, xy, x^2, y^2}.
// grid = B_ROWS * SPLIT blocks. float4 coalesced loads.
// ---------------------------------------------------------------------------
__global__ __launch_bounds__(NTHREADS) void pearson_partial(
    const float* __restrict__ preds,
    const float* __restrict__ labels,
    float* __restrict__ ws,   // [B_ROWS*SPLIT][5]
    int N)
{
    const int row = blockIdx.x / SPLIT;
    const int seg = blockIdx.x % SPLIT;
    const int tid = threadIdx.x;

    const int n4      = N / 4;         // 25000 float4 per row (N % 4 == 0)
    const int per_seg = n4 / SPLIT;    // 3125 (exact)
    const int begin   = seg * per_seg;
    const int end     = begin + per_seg;

    const float4* p4 = reinterpret_cast<const float4*>(preds  + (size_t)row * N);
    const float4* l4 = reinterpret_cast<const float4*>(labels + (size_t)row * N);

    float sx = 0.f, sy = 0.f, sxy = 0.f, sxx = 0.f, syy = 0.f;

    for (int i = begin + tid; i < end; i += NTHREADS) {
        float4 a = p4[i];
        float4 b = l4[i];
        sx += a.x; sy += b.x; sxy = fmaf(a.x, b.x, sxy); sxx = fmaf(a.x, a.x, sxx); syy = fmaf(b.x, b.x, syy);
        sx += a.y; sy += b.y; sxy = fmaf(a.y, b.y, sxy); sxx = fmaf(a.y, a.y, sxx); syy = fmaf(b.y, b.y, syy);
        sx += a.z; sy += b.z; sxy = fmaf(a.z, b.z, sxy); sxx = fmaf(a.z, a.z, sxx); syy = fmaf(b.z, b.z, syy);
        sx += a.w; sy += b.w; sxy = fmaf(a.w, b.w, sxy); sxx = fmaf(a.w, a.w, sxx); syy = fmaf(b.w, b.w, syy);
    }

    // wave-64 butterfly reduction
    for (int o = 32; o > 0; o >>= 1) {
        sx  += __shfl_down(sx,  o, 64);
        sy  += __shfl_down(sy,  o, 64);
        sxy += __shfl_down(sxy, o, 64);
        sxx += __shfl_down(sxx, o, 64);
        syy += __shfl_down(syy, o, 64);
    }

    __shared__ float red[4][5];
    const int wave = tid >> 6;
    const int lane = tid & 63;
    if (lane == 0) {
        red[wave][0] = sx;  red[wave][1] = sy;  red[wave][2] = sxy;
        red[wave][3] = sxx; red[wave][4] = syy;
    }
    __syncthreads();

    if (tid == 0) {
        float t0 = red[0][0] + red[1][0] + red[2][0] + red[3][0];
        float t1 = red[0][1] + red[1][1] + red[2][1] + red[3][1];
        float t2 = red[0][2] + red[1][2] + red[2][2] + red[3][2];
        float t3 = red[0][3] + red[1][3] + red[2][3] + red[3][3];
        float t4 = red[0][4] + red[1][4] + red[2][4] + red[3][4];
        float* w = ws + (size_t)blockIdx.x * 5;
        w[0] = t0; w[1] = t1; w[2] = t2; w[3] = t3; w[4] = t4;
    }
}

// ---------------------------------------------------------------------------
// Kernel 2: combine SPLIT partials per row (double), compute 1 - pearson,
// mean over rows. 1 block x 256 threads (one thread per row).
// ---------------------------------------------------------------------------
__global__ __launch_bounds__(NTHREADS) void pearson_final(
    const float* __restrict__ ws,
    float* __restrict__ out,
    int N)
{
    const int t = threadIdx.x;   // row index

    double sx = 0.0, sy = 0.0, sxy = 0.0, sxx = 0.0, syy = 0.0;
    for (int s = 0; s < SPLIT; ++s) {
        const float* w = ws + ((size_t)t * SPLIT + s) * 5;
        sx  += (double)w[0];
        sy  += (double)w[1];
        sxy += (double)w[2];
        sxx += (double)w[3];
        syy += (double)w[4];
    }

    const double n   = (double)N;
    const double num = n * sxy - sx * sy;
    const double den = sqrt((n * sxx - sx * sx) * (n * syy - sy * sy));
    double val = 1.0 - num / den;

    // block reduction of val over 256 threads
    for (int o = 32; o > 0; o >>= 1)
        val += __shfl_down(val, o, 64);

    __shared__ double red[4];
    const int wave = t >> 6;
    const int lane = t & 63;
    if (lane == 0) red[wave] = val;
    __syncthreads();

    if (t == 0) {
        double total = red[0] + red[1] + red[2] + red[3];
        out[0] = (float)(total / (double)B_ROWS);
    }
}

// ---------------------------------------------------------------------------
extern "C" void kernel_launch(void* const* d_in, const int* in_sizes, int n_in,
                              void* d_out, int out_size, void* d_ws, size_t ws_size,
                              hipStream_t stream)
{
    const float* preds  = (const float*)d_in[0];
    const float* labels = (const float*)d_in[1];
    // d_in[2] = subject (scalar int), unused by the math.

    const int N = in_sizes[0] / B_ROWS;   // 100000

    float* ws  = (float*)d_ws;            // B_ROWS*SPLIT*5 floats = 40 KiB
    float* out = (float*)d_out;

    pearson_partial<<<B_ROWS * SPLIT, NTHREADS, 0, stream>>>(preds, labels, ws, N);
    pearson_final<<<1, NTHREADS, 0, stream>>>(ws, out, N);
}